// Round 10
// baseline (576.667 us; speedup 1.0000x reference)
//
#include <hip/hip_runtime.h>
#include <hip/hip_bf16.h>

#ifndef NEG_SLOPE
#define NEG_SLOPE 0.2f
#endif

static inline int cdiv(long long a, long long b) { return (int)((a + b - 1) / b); }

__device__ __forceinline__ float lrelu(float v) { return v > 0.f ? v : NEG_SLOPE * v; }

// ---- merged prep: blocks 0-2 build extended weights (layer b), blocks 3+ do degree count.
// wext rows [0,FOUT) = W; row FOUT+h = (W^T al) fold; row FOUT+H+h = (W^T ar) fold.
__global__ void k_prep(const float* __restrict__ W1, const float* __restrict__ al1,
                       const float* __restrict__ ar1, const float* __restrict__ W2,
                       const float* __restrict__ al2, const float* __restrict__ ar2,
                       const float* __restrict__ W3, const float* __restrict__ al3,
                       const float* __restrict__ ar3, float* __restrict__ wx1,
                       float* __restrict__ wx2, float* __restrict__ wx3,
                       const int* __restrict__ dst, int* __restrict__ deg, int n_edges) {
    if (blockIdx.x < 3) {
        int b = blockIdx.x;
        const float *W, *al, *ar;
        float* wx;
        int FIN, FOUT, H, D;
        if (b == 0) { W = W1; al = al1; ar = ar1; wx = wx1; FIN = 25; FOUT = 40; H = 4; D = 10; }
        else if (b == 1) { W = W2; al = al2; ar = ar2; wx = wx2; FIN = 40; FOUT = 100; H = 4; D = 25; }
        else { W = W3; al = al3; ar = ar3; wx = wx3; FIN = 100; FOUT = 50; H = 1; D = 50; }
        for (int i = threadIdx.x; i < FOUT * FIN; i += blockDim.x) wx[i] = W[i];
        for (int i = threadIdx.x; i < 2 * H * FIN; i += blockDim.x) {
            int row = i / FIN, k = i % FIN;
            int h = row % H, isR = row / H;
            const float* a = isR ? ar : al;
            float s = 0.f;
            for (int d = 0; d < D; ++d) s += W[(h * D + d) * FIN + k] * a[h * D + d];
            wx[(FOUT + isR * H + h) * FIN + k] = s;
        }
    } else {
        int e = (blockIdx.x - 3) * blockDim.x + threadIdx.x;
        if (e < n_edges) atomicAdd(&deg[dst[e]], 1);
    }
}

// ---- single-block exclusive scan: rowptr[i] = sum_{j<i} deg[j]; rowptr[n] = n_edges
__global__ void k_scan_one(const int* __restrict__ deg, int* __restrict__ rowptr, int n,
                           int n_edges) {
    __shared__ int sums[256];
    int t = threadIdx.x;
    int chunk = (n + 255) / 256;
    int lo = t * chunk, hi = lo + chunk;
    if (hi > n) hi = n;
    int s = 0;
    for (int i = lo; i < hi; ++i) s += deg[i];
    sums[t] = s;
    __syncthreads();
    for (int off = 1; off < 256; off <<= 1) {
        int add = (t >= off) ? sums[t - off] : 0;
        __syncthreads();
        sums[t] += add;
        __syncthreads();
    }
    int run = (t > 0) ? sums[t - 1] : 0;
    for (int i = lo; i < hi; ++i) {
        rowptr[i] = run;
        run += deg[i];
    }
    if (t == 0) rowptr[n] = n_edges;
}

// ---- fused linear + scores: one pass produces h, el, er from wext
template <int FIN, int FOUT, int H>
__global__ void k_linear(const float* __restrict__ x, const float* __restrict__ wx,
                         float* __restrict__ h, float* __restrict__ el, float* __restrict__ er,
                         int n_nodes) {
    constexpr int FOUTE = FOUT + 2 * H;
    __shared__ float Ws[FIN * FOUTE];
    for (int i = threadIdx.x; i < FIN * FOUTE; i += blockDim.x) {
        int f = i / FIN, k = i % FIN;
        Ws[k * FOUTE + f] = wx[i];
    }
    __syncthreads();
    int idx = blockIdx.x * blockDim.x + threadIdx.x;
    if (idx >= n_nodes * FOUTE) return;
    int n = idx / FOUTE, f = idx % FOUTE;
    const float* __restrict__ xr = x + (long long)n * FIN;
    float acc = 0.f;
#pragma unroll
    for (int k = 0; k < FIN; ++k) acc += xr[k] * Ws[k * FOUTE + f];
    if (f < FOUT) h[(long long)n * FOUT + f] = acc;
    else if (f < FOUT + H) el[n * H + (f - FOUT)] = acc;
    else er[n * H + (f - FOUT - H)] = acc;
}

__global__ void k_fill(const int* __restrict__ src, const int* __restrict__ dst,
                       const int* __restrict__ rowptr, int* __restrict__ cursor,
                       int* __restrict__ csr_src, int n_edges) {
    int e = blockIdx.x * blockDim.x + threadIdx.x;
    if (e >= n_edges) return;
    int d = dst[e];
    int pos = atomicAdd(&cursor[d], 1);
    csr_src[rowptr[d] + pos] = src[e];
}

// wave-parallel rank sort: one wave per node (deterministic sorted order).
__global__ void k_sort_wave(const int* __restrict__ rowptr, int* __restrict__ csr_src,
                            int n_nodes) {
    int wid = (blockIdx.x * blockDim.x + threadIdx.x) >> 6;
    int lane = threadIdx.x & 63;
    if (wid >= n_nodes) return;
    int s0 = rowptr[wid], e0 = rowptr[wid + 1];
    int d = e0 - s0;
    if (d <= 1) return;
    if (d <= 64) {
        int v = (lane < d) ? csr_src[s0 + lane] : 0x7FFFFFFF;
        int rank = 0;
        for (int k = 0; k < d; ++k) {
            int vk = __shfl(v, k);
            rank += (vk < v || (vk == v && k < lane)) ? 1 : 0;
        }
        if (lane < d) csr_src[s0 + rank] = v;
    } else if (lane == 0) {
        for (int a = s0 + 1; a < e0; ++a) {
            int key = csr_src[a];
            int b = a - 1;
            while (b >= s0 && csr_src[b] > key) { csr_src[b + 1] = csr_src[b]; --b; }
            csr_src[b + 1] = key;
        }
    }
}

// ================= fused per-node attention (r7 body, proven 78.4us floor) ============
// alpha = exp(v)/sum(exp(v)) (== exp(v-m)/sum form exactly; |v| ~<25 here, no overflow).
// One wave per dst node.
//   p-role: lane -> edge slot lane/H, head lane%H  (EB*H <= 64 slots).
//   f-role: slot r owns feature f = lane + r*64 (per-slot guard, r=0 wave-uniform —
//           proven no-spill form; do NOT collapse to a single isF guard).
template <int FOUT, int H, int D, int EB>
__global__ void k_node_gather(const int* __restrict__ rowptr, const int* __restrict__ csr_src,
                              const float* __restrict__ el, const float* __restrict__ er,
                              const float* __restrict__ h, const float* __restrict__ bias,
                              float* __restrict__ xout, int n_nodes) {
    constexpr int NF = (FOUT + 63) / 64;
    int wid = (blockIdx.x * blockDim.x + threadIdx.x) >> 6;
    int lane = threadIdx.x & 63;
    if (wid >= n_nodes) return;
    int start = rowptr[wid], end = rowptr[wid + 1];

    const int eidx = lane / H;
    const int hh_c = lane % H;
    const float er_c = er[wid * H + hh_c];

    float acc[NF];
    int f_i[NF], hh_i[NF];
#pragma unroll
    for (int r = 0; r < NF; ++r) {
        int f = lane + r * 64;
        f_i[r] = f;
        hh_i[r] = (f < FOUT) ? (f / D) : 0;
        acc[r] = 0.f;
    }
    float den_acc = 0.f;

    if (start < end) {
        int j0 = start;
        int nb = end - j0;
        if (nb > EB) nb = EB;
        int s_c = csr_src[j0 + (eidx < nb ? eidx : 0)];
        float e_c = el[s_c * H + hh_c];

        while (true) {
            int j1 = j0 + nb;
            int nbn = end - j1;
            if (nbn > EB) nbn = EB;
            int s_n = 0;
            float e_n = 0.f;
            if (nbn > 0) {  // prefetch next batch ids + el (hides latency under FMAs)
                s_n = csr_src[j1 + (eidx < nbn ? eidx : 0)];
                e_n = el[s_n * H + hh_c];
            }
            // probability (one per p-slot) + butterfly denominator
            float p_c = expf(lrelu(e_c + er_c));
            float pd = (eidx < nb) ? p_c : 0.f;
#pragma unroll
            for (int st = H; st < 64; st <<= 1) pd += __shfl_xor(pd, st);
            den_acc += pd;

            // burst-load edge rows into flat register buffer (static indexing)
            float hv[EB * NF];
#pragma unroll
            for (int e = 0; e < EB; ++e) {
                if (e < nb) {  // nb wave-uniform
                    int s = __shfl(s_c, e * H);
                    const float* __restrict__ hrow = h + (long long)s * FOUT;
#pragma unroll
                    for (int r = 0; r < NF; ++r)
                        if (f_i[r] < FOUT) hv[e * NF + r] = hrow[f_i[r]];
                }
            }
            // consume
#pragma unroll
            for (int e = 0; e < EB; ++e) {
                if (e < nb) {
#pragma unroll
                    for (int r = 0; r < NF; ++r) {
                        float p = __shfl(p_c, e * H + hh_i[r]);
                        if (f_i[r] < FOUT) acc[r] += p * hv[e * NF + r];
                    }
                }
            }
            if (nbn <= 0) break;
            j0 = j1;
            nb = nbn;
            s_c = s_n;
            e_c = e_n;
        }
    }

    // epilogue: den shfls hoisted outside the divergent f-guard
    float den_r[NF];
#pragma unroll
    for (int r = 0; r < NF; ++r) den_r[r] = __shfl(den_acc, hh_i[r]);
#pragma unroll
    for (int r = 0; r < NF; ++r) {
        if (f_i[r] < FOUT) {
            float val;
            if (end > start) val = acc[r] / den_r[r] + bias[f_i[r]];
            else val = bias[f_i[r]];
            xout[(long long)wid * FOUT + f_i[r]] = val > 0.f ? val : 0.f;
        }
    }
}

// ---- final FC: out = x @ W.T + b (transposed LDS staging)
template <int FIN, int FOUT>
__global__ void k_fc(const float* __restrict__ x, const float* __restrict__ W,
                     const float* __restrict__ b, float* __restrict__ out, int n_nodes) {
    __shared__ float Ws[FIN * FOUT];
    for (int i = threadIdx.x; i < FIN * FOUT; i += blockDim.x) {
        int f = i / FIN, k = i % FIN;
        Ws[k * FOUT + f] = W[i];
    }
    __syncthreads();
    int idx = blockIdx.x * blockDim.x + threadIdx.x;
    if (idx >= n_nodes * FOUT) return;
    int n = idx / FOUT, f = idx % FOUT;
    const float* __restrict__ xr = x + (long long)n * FIN;
    float acc = b[f];
#pragma unroll
    for (int k = 0; k < FIN; ++k) acc += xr[k] * Ws[k * FOUT + f];
    out[idx] = acc;
}

template <int FIN, int FOUT, int H, int D, int EB>
static void gat_layer(const float* x, const float* wext, const float* bias, const int* rowptr,
                      const int* csr_src, int n_nodes, float* bufH, float* el, float* er,
                      float* xnext, hipStream_t stream) {
    constexpr int FOUTE = FOUT + 2 * H;
    k_linear<FIN, FOUT, H><<<cdiv((long long)n_nodes * FOUTE, 256), 256, 0, stream>>>(
        x, wext, bufH, el, er, n_nodes);
    k_node_gather<FOUT, H, D, EB><<<cdiv((long long)n_nodes * 64, 256), 256, 0, stream>>>(
        rowptr, csr_src, el, er, bufH, bias, xnext, n_nodes);
}

extern "C" void kernel_launch(void* const* d_in, const int* in_sizes, int n_in,
                              void* d_out, int out_size, void* d_ws, size_t ws_size,
                              hipStream_t stream) {
    const float* features = (const float*)d_in[0];
    const int* src = (const int*)d_in[1];
    const int* dst = (const int*)d_in[2];
    const float* W1 = (const float*)d_in[3];
    const float* al1 = (const float*)d_in[4];
    const float* ar1 = (const float*)d_in[5];
    const float* b1 = (const float*)d_in[6];
    const float* W2 = (const float*)d_in[7];
    const float* al2 = (const float*)d_in[8];
    const float* ar2 = (const float*)d_in[9];
    const float* b2 = (const float*)d_in[10];
    const float* W3 = (const float*)d_in[11];
    const float* al3 = (const float*)d_in[12];
    const float* ar3 = (const float*)d_in[13];
    const float* b3 = (const float*)d_in[14];
    const float* fc_w = (const float*)d_in[15];
    const float* fc_b = (const float*)d_in[16];

    const int n_nodes = in_sizes[0] / 25;  // 50000
    const int n_edges = in_sizes[1];       // 1000000

    char* ws = (char*)d_ws;
    size_t off = 0;
    auto alloc = [&](size_t bytes) {
        char* p = ws + off;
        off += (bytes + 255) & ~(size_t)255;
        return p;
    };
    float* bufA = (float*)alloc((size_t)n_nodes * 100 * sizeof(float));
    float* bufH = (float*)alloc((size_t)n_nodes * 100 * sizeof(float));
    float* el = (float*)alloc((size_t)n_nodes * 4 * sizeof(float));
    float* er = (float*)alloc((size_t)n_nodes * 4 * sizeof(float));
    int* degcur = (int*)alloc((size_t)2 * n_nodes * sizeof(int));  // deg | cursor
    int* deg = degcur;
    int* cursor = degcur + n_nodes;
    int* rowptr = (int*)alloc((size_t)(n_nodes + 1) * sizeof(int));
    int* csr_src = (int*)alloc((size_t)n_edges * sizeof(int));
    float* wx1 = (float*)alloc((size_t)48 * 25 * sizeof(float));
    float* wx2 = (float*)alloc((size_t)108 * 40 * sizeof(float));
    float* wx3 = (float*)alloc((size_t)52 * 100 * sizeof(float));
    (void)ws_size;

    // ---- prep: zero deg/cursor, then wext (blocks 0-2) + degree count (blocks 3+)
    hipMemsetAsync(degcur, 0, (size_t)2 * n_nodes * sizeof(int), stream);
    k_prep<<<3 + cdiv(n_edges, 256), 256, 0, stream>>>(W1, al1, ar1, W2, al2, ar2, W3, al3,
                                                       ar3, wx1, wx2, wx3, dst, deg, n_edges);
    k_scan_one<<<1, 256, 0, stream>>>(deg, rowptr, n_nodes, n_edges);
    k_fill<<<cdiv(n_edges, 256), 256, 0, stream>>>(src, dst, rowptr, cursor, csr_src, n_edges);
    k_sort_wave<<<cdiv((long long)n_nodes * 64, 256), 256, 0, stream>>>(rowptr, csr_src,
                                                                        n_nodes);

    // ---- 3 GAT layers
    gat_layer<25, 40, 4, 10, 16>(features, wx1, b1, rowptr, csr_src, n_nodes, bufH, el, er,
                                 bufA, stream);
    gat_layer<40, 100, 4, 25, 16>(bufA, wx2, b2, rowptr, csr_src, n_nodes, bufH, el, er,
                                  bufA, stream);
    gat_layer<100, 50, 1, 50, 32>(bufA, wx3, b3, rowptr, csr_src, n_nodes, bufH, el, er,
                                  bufA, stream);

    // ---- final FC: 50 -> 93
    k_fc<50, 93><<<cdiv((long long)n_nodes * 93, 256), 256, 0, stream>>>(
        bufA, fc_w, fc_b, (float*)d_out, n_nodes);
}

// Round 11
// 512.646 us; speedup vs baseline: 1.1249x; 1.1249x over previous
//
#include <hip/hip_runtime.h>
#include <hip/hip_bf16.h>

#ifndef NEG_SLOPE
#define NEG_SLOPE 0.2f
#endif

static inline int cdiv(long long a, long long b) { return (int)((a + b - 1) / b); }

__device__ __forceinline__ float lrelu(float v) { return v > 0.f ? v : NEG_SLOPE * v; }

// ---- merged prep: blocks 0-2 build extended weights (layer b), blocks 3+ do degree count.
// wext rows [0,FOUT) = W; row FOUT+h = (W^T al) fold; row FOUT+H+h = (W^T ar) fold.
__global__ void k_prep(const float* __restrict__ W1, const float* __restrict__ al1,
                       const float* __restrict__ ar1, const float* __restrict__ W2,
                       const float* __restrict__ al2, const float* __restrict__ ar2,
                       const float* __restrict__ W3, const float* __restrict__ al3,
                       const float* __restrict__ ar3, float* __restrict__ wx1,
                       float* __restrict__ wx2, float* __restrict__ wx3,
                       const int* __restrict__ dst, int* __restrict__ deg, int n_edges) {
    if (blockIdx.x < 3) {
        int b = blockIdx.x;
        const float *W, *al, *ar;
        float* wx;
        int FIN, FOUT, H, D;
        if (b == 0) { W = W1; al = al1; ar = ar1; wx = wx1; FIN = 25; FOUT = 40; H = 4; D = 10; }
        else if (b == 1) { W = W2; al = al2; ar = ar2; wx = wx2; FIN = 40; FOUT = 100; H = 4; D = 25; }
        else { W = W3; al = al3; ar = ar3; wx = wx3; FIN = 100; FOUT = 50; H = 1; D = 50; }
        for (int i = threadIdx.x; i < FOUT * FIN; i += blockDim.x) wx[i] = W[i];
        for (int i = threadIdx.x; i < 2 * H * FIN; i += blockDim.x) {
            int row = i / FIN, k = i % FIN;
            int h = row % H, isR = row / H;
            const float* a = isR ? ar : al;
            float s = 0.f;
            for (int d = 0; d < D; ++d) s += W[(h * D + d) * FIN + k] * a[h * D + d];
            wx[(FOUT + isR * H + h) * FIN + k] = s;
        }
    } else {
        int e = (blockIdx.x - 3) * blockDim.x + threadIdx.x;
        if (e < n_edges) atomicAdd(&deg[dst[e]], 1);
    }
}

// ---- 3-kernel scan cascade (proven ~10us total; single-block scan was 86us — do not merge)
__global__ void k_scan_block(const int* __restrict__ deg, int* __restrict__ incl,
                             int* __restrict__ blocksum, int n) {
    __shared__ int tmp[256];
    int t = threadIdx.x;
    int i = blockIdx.x * 256 + t;
    int v = (i < n) ? deg[i] : 0;
    tmp[t] = v;
    __syncthreads();
    for (int off = 1; off < 256; off <<= 1) {
        int add = (t >= off) ? tmp[t - off] : 0;
        __syncthreads();
        tmp[t] += add;
        __syncthreads();
    }
    if (i < n) incl[i] = tmp[t];
    if (t == 255) blocksum[blockIdx.x] = tmp[t];
}

__global__ void k_scan_top(const int* __restrict__ blocksum, int* __restrict__ blockoff, int nb) {
    __shared__ int tmp[256];
    int t = threadIdx.x;
    int base = 0;
    for (int c = 0; c < nb; c += 256) {
        int i = c + t;
        int v = (i < nb) ? blocksum[i] : 0;
        tmp[t] = v;
        __syncthreads();
        for (int off = 1; off < 256; off <<= 1) {
            int add = (t >= off) ? tmp[t - off] : 0;
            __syncthreads();
            tmp[t] += add;
            __syncthreads();
        }
        if (i < nb) blockoff[i] = base + tmp[t] - v;
        base += tmp[255];
        __syncthreads();
    }
}

__global__ void k_scan_finalize(const int* __restrict__ incl, const int* __restrict__ deg,
                                const int* __restrict__ blockoff, int* __restrict__ rowptr,
                                int n, int n_edges) {
    int i = blockIdx.x * blockDim.x + threadIdx.x;
    if (i < n) rowptr[i] = incl[i] - deg[i] + blockoff[i / 256];
    if (i == 0) rowptr[n] = n_edges;
}

// ---- fused linear + scores: one pass produces h, el, er from wext
template <int FIN, int FOUT, int H>
__global__ void k_linear(const float* __restrict__ x, const float* __restrict__ wx,
                         float* __restrict__ h, float* __restrict__ el, float* __restrict__ er,
                         int n_nodes) {
    constexpr int FOUTE = FOUT + 2 * H;
    __shared__ float Ws[FIN * FOUTE];
    for (int i = threadIdx.x; i < FIN * FOUTE; i += blockDim.x) {
        int f = i / FIN, k = i % FIN;
        Ws[k * FOUTE + f] = wx[i];
    }
    __syncthreads();
    int idx = blockIdx.x * blockDim.x + threadIdx.x;
    if (idx >= n_nodes * FOUTE) return;
    int n = idx / FOUTE, f = idx % FOUTE;
    const float* __restrict__ xr = x + (long long)n * FIN;
    float acc = 0.f;
#pragma unroll
    for (int k = 0; k < FIN; ++k) acc += xr[k] * Ws[k * FOUTE + f];
    if (f < FOUT) h[(long long)n * FOUT + f] = acc;
    else if (f < FOUT + H) el[n * H + (f - FOUT)] = acc;
    else er[n * H + (f - FOUT - H)] = acc;
}

__global__ void k_fill(const int* __restrict__ src, const int* __restrict__ dst,
                       const int* __restrict__ rowptr, int* __restrict__ cursor,
                       int* __restrict__ csr_src, int n_edges) {
    int e = blockIdx.x * blockDim.x + threadIdx.x;
    if (e >= n_edges) return;
    int d = dst[e];
    int pos = atomicAdd(&cursor[d], 1);
    csr_src[rowptr[d] + pos] = src[e];
}

// wave-parallel rank sort: one wave per node (deterministic sorted order).
__global__ void k_sort_wave(const int* __restrict__ rowptr, int* __restrict__ csr_src,
                            int n_nodes) {
    int wid = (blockIdx.x * blockDim.x + threadIdx.x) >> 6;
    int lane = threadIdx.x & 63;
    if (wid >= n_nodes) return;
    int s0 = rowptr[wid], e0 = rowptr[wid + 1];
    int d = e0 - s0;
    if (d <= 1) return;
    if (d <= 64) {
        int v = (lane < d) ? csr_src[s0 + lane] : 0x7FFFFFFF;
        int rank = 0;
        for (int k = 0; k < d; ++k) {
            int vk = __shfl(v, k);
            rank += (vk < v || (vk == v && k < lane)) ? 1 : 0;
        }
        if (lane < d) csr_src[s0 + rank] = v;
    } else if (lane == 0) {
        for (int a = s0 + 1; a < e0; ++a) {
            int key = csr_src[a];
            int b = a - 1;
            while (b >= s0 && csr_src[b] > key) { csr_src[b + 1] = csr_src[b]; --b; }
            csr_src[b + 1] = key;
        }
    }
}

// ================= fused per-node attention (r7 body, proven 78.4us floor) ============
// alpha = exp(v)/sum(exp(v)) (== exp(v-m)/sum form exactly; |v| ~<25 here, no overflow).
// One wave per dst node.
//   p-role: lane -> edge slot lane/H, head lane%H  (EB*H <= 64 slots).
//   f-role: slot r owns feature f = lane + r*64 (per-slot guard, r=0 wave-uniform —
//           proven no-spill form; do NOT collapse to a single isF guard).
template <int FOUT, int H, int D, int EB>
__global__ void k_node_gather(const int* __restrict__ rowptr, const int* __restrict__ csr_src,
                              const float* __restrict__ el, const float* __restrict__ er,
                              const float* __restrict__ h, const float* __restrict__ bias,
                              float* __restrict__ xout, int n_nodes) {
    constexpr int NF = (FOUT + 63) / 64;
    int wid = (blockIdx.x * blockDim.x + threadIdx.x) >> 6;
    int lane = threadIdx.x & 63;
    if (wid >= n_nodes) return;
    int start = rowptr[wid], end = rowptr[wid + 1];

    const int eidx = lane / H;
    const int hh_c = lane % H;
    const float er_c = er[wid * H + hh_c];

    float acc[NF];
    int f_i[NF], hh_i[NF];
#pragma unroll
    for (int r = 0; r < NF; ++r) {
        int f = lane + r * 64;
        f_i[r] = f;
        hh_i[r] = (f < FOUT) ? (f / D) : 0;
        acc[r] = 0.f;
    }
    float den_acc = 0.f;

    if (start < end) {
        int j0 = start;
        int nb = end - j0;
        if (nb > EB) nb = EB;
        int s_c = csr_src[j0 + (eidx < nb ? eidx : 0)];
        float e_c = el[s_c * H + hh_c];

        while (true) {
            int j1 = j0 + nb;
            int nbn = end - j1;
            if (nbn > EB) nbn = EB;
            int s_n = 0;
            float e_n = 0.f;
            if (nbn > 0) {  // prefetch next batch ids + el (hides latency under FMAs)
                s_n = csr_src[j1 + (eidx < nbn ? eidx : 0)];
                e_n = el[s_n * H + hh_c];
            }
            // probability (one per p-slot) + butterfly denominator
            float p_c = expf(lrelu(e_c + er_c));
            float pd = (eidx < nb) ? p_c : 0.f;
#pragma unroll
            for (int st = H; st < 64; st <<= 1) pd += __shfl_xor(pd, st);
            den_acc += pd;

            // burst-load edge rows into flat register buffer (static indexing)
            float hv[EB * NF];
#pragma unroll
            for (int e = 0; e < EB; ++e) {
                if (e < nb) {  // nb wave-uniform
                    int s = __shfl(s_c, e * H);
                    const float* __restrict__ hrow = h + (long long)s * FOUT;
#pragma unroll
                    for (int r = 0; r < NF; ++r)
                        if (f_i[r] < FOUT) hv[e * NF + r] = hrow[f_i[r]];
                }
            }
            // consume
#pragma unroll
            for (int e = 0; e < EB; ++e) {
                if (e < nb) {
#pragma unroll
                    for (int r = 0; r < NF; ++r) {
                        float p = __shfl(p_c, e * H + hh_i[r]);
                        if (f_i[r] < FOUT) acc[r] += p * hv[e * NF + r];
                    }
                }
            }
            if (nbn <= 0) break;
            j0 = j1;
            nb = nbn;
            s_c = s_n;
            e_c = e_n;
        }
    }

    // epilogue: den shfls hoisted outside the divergent f-guard
    float den_r[NF];
#pragma unroll
    for (int r = 0; r < NF; ++r) den_r[r] = __shfl(den_acc, hh_i[r]);
#pragma unroll
    for (int r = 0; r < NF; ++r) {
        if (f_i[r] < FOUT) {
            float val;
            if (end > start) val = acc[r] / den_r[r] + bias[f_i[r]];
            else val = bias[f_i[r]];
            xout[(long long)wid * FOUT + f_i[r]] = val > 0.f ? val : 0.f;
        }
    }
}

// ---- final FC: out = x @ W.T + b (transposed LDS staging)
template <int FIN, int FOUT>
__global__ void k_fc(const float* __restrict__ x, const float* __restrict__ W,
                     const float* __restrict__ b, float* __restrict__ out, int n_nodes) {
    __shared__ float Ws[FIN * FOUT];
    for (int i = threadIdx.x; i < FIN * FOUT; i += blockDim.x) {
        int f = i / FIN, k = i % FIN;
        Ws[k * FOUT + f] = W[i];
    }
    __syncthreads();
    int idx = blockIdx.x * blockDim.x + threadIdx.x;
    if (idx >= n_nodes * FOUT) return;
    int n = idx / FOUT, f = idx % FOUT;
    const float* __restrict__ xr = x + (long long)n * FIN;
    float acc = b[f];
#pragma unroll
    for (int k = 0; k < FIN; ++k) acc += xr[k] * Ws[k * FOUT + f];
    out[idx] = acc;
}

template <int FIN, int FOUT, int H, int D, int EB>
static void gat_layer(const float* x, const float* wext, const float* bias, const int* rowptr,
                      const int* csr_src, int n_nodes, float* bufH, float* el, float* er,
                      float* xnext, hipStream_t stream) {
    constexpr int FOUTE = FOUT + 2 * H;
    k_linear<FIN, FOUT, H><<<cdiv((long long)n_nodes * FOUTE, 256), 256, 0, stream>>>(
        x, wext, bufH, el, er, n_nodes);
    k_node_gather<FOUT, H, D, EB><<<cdiv((long long)n_nodes * 64, 256), 256, 0, stream>>>(
        rowptr, csr_src, el, er, bufH, bias, xnext, n_nodes);
}

extern "C" void kernel_launch(void* const* d_in, const int* in_sizes, int n_in,
                              void* d_out, int out_size, void* d_ws, size_t ws_size,
                              hipStream_t stream) {
    const float* features = (const float*)d_in[0];
    const int* src = (const int*)d_in[1];
    const int* dst = (const int*)d_in[2];
    const float* W1 = (const float*)d_in[3];
    const float* al1 = (const float*)d_in[4];
    const float* ar1 = (const float*)d_in[5];
    const float* b1 = (const float*)d_in[6];
    const float* W2 = (const float*)d_in[7];
    const float* al2 = (const float*)d_in[8];
    const float* ar2 = (const float*)d_in[9];
    const float* b2 = (const float*)d_in[10];
    const float* W3 = (const float*)d_in[11];
    const float* al3 = (const float*)d_in[12];
    const float* ar3 = (const float*)d_in[13];
    const float* b3 = (const float*)d_in[14];
    const float* fc_w = (const float*)d_in[15];
    const float* fc_b = (const float*)d_in[16];

    const int n_nodes = in_sizes[0] / 25;  // 50000
    const int n_edges = in_sizes[1];       // 1000000
    const int nblocks_nodes = cdiv(n_nodes, 256);

    char* ws = (char*)d_ws;
    size_t off = 0;
    auto alloc = [&](size_t bytes) {
        char* p = ws + off;
        off += (bytes + 255) & ~(size_t)255;
        return p;
    };
    float* bufA = (float*)alloc((size_t)n_nodes * 100 * sizeof(float));
    float* bufH = (float*)alloc((size_t)n_nodes * 100 * sizeof(float));
    float* el = (float*)alloc((size_t)n_nodes * 4 * sizeof(float));
    float* er = (float*)alloc((size_t)n_nodes * 4 * sizeof(float));
    int* degcur = (int*)alloc((size_t)2 * n_nodes * sizeof(int));  // deg | cursor
    int* deg = degcur;
    int* cursor = degcur + n_nodes;
    int* incl = (int*)alloc((size_t)n_nodes * sizeof(int));
    int* blocksum = (int*)alloc((size_t)nblocks_nodes * sizeof(int));
    int* blockoff = (int*)alloc((size_t)nblocks_nodes * sizeof(int));
    int* rowptr = (int*)alloc((size_t)(n_nodes + 1) * sizeof(int));
    int* csr_src = (int*)alloc((size_t)n_edges * sizeof(int));
    float* wx1 = (float*)alloc((size_t)48 * 25 * sizeof(float));
    float* wx2 = (float*)alloc((size_t)108 * 40 * sizeof(float));
    float* wx3 = (float*)alloc((size_t)52 * 100 * sizeof(float));
    (void)ws_size;

    // ---- prep: zero deg/cursor, then wext (blocks 0-2) + degree count (blocks 3+)
    hipMemsetAsync(degcur, 0, (size_t)2 * n_nodes * sizeof(int), stream);
    k_prep<<<3 + cdiv(n_edges, 256), 256, 0, stream>>>(W1, al1, ar1, W2, al2, ar2, W3, al3,
                                                       ar3, wx1, wx2, wx3, dst, deg, n_edges);
    k_scan_block<<<nblocks_nodes, 256, 0, stream>>>(deg, incl, blocksum, n_nodes);
    k_scan_top<<<1, 256, 0, stream>>>(blocksum, blockoff, nblocks_nodes);
    k_scan_finalize<<<cdiv(n_nodes + 1, 256), 256, 0, stream>>>(incl, deg, blockoff, rowptr,
                                                                n_nodes, n_edges);
    k_fill<<<cdiv(n_edges, 256), 256, 0, stream>>>(src, dst, rowptr, cursor, csr_src, n_edges);
    k_sort_wave<<<cdiv((long long)n_nodes * 64, 256), 256, 0, stream>>>(rowptr, csr_src,
                                                                        n_nodes);

    // ---- 3 GAT layers
    gat_layer<25, 40, 4, 10, 16>(features, wx1, b1, rowptr, csr_src, n_nodes, bufH, el, er,
                                 bufA, stream);
    gat_layer<40, 100, 4, 25, 16>(bufA, wx2, b2, rowptr, csr_src, n_nodes, bufH, el, er,
                                  bufA, stream);
    gat_layer<100, 50, 1, 50, 32>(bufA, wx3, b3, rowptr, csr_src, n_nodes, bufH, el, er,
                                  bufA, stream);

    // ---- final FC: 50 -> 93
    k_fc<50, 93><<<cdiv((long long)n_nodes * 93, 256), 256, 0, stream>>>(
        bufA, fc_w, fc_b, (float*)d_out, n_nodes);
}

// Round 12
// 509.676 us; speedup vs baseline: 1.1314x; 1.0058x over previous
//
#include <hip/hip_runtime.h>
#include <hip/hip_bf16.h>

#ifndef NEG_SLOPE
#define NEG_SLOPE 0.2f
#endif

static inline int cdiv(long long a, long long b) { return (int)((a + b - 1) / b); }

__device__ __forceinline__ float lrelu(float v) { return v > 0.f ? v : NEG_SLOPE * v; }

// ---- merged prep: blocks 0-2 build extended weights (layer b), blocks 3+ do degree count.
// wext rows [0,FOUT) = W; row FOUT+h = (W^T al) fold; row FOUT+H+h = (W^T ar) fold.
__global__ void k_prep(const float* __restrict__ W1, const float* __restrict__ al1,
                       const float* __restrict__ ar1, const float* __restrict__ W2,
                       const float* __restrict__ al2, const float* __restrict__ ar2,
                       const float* __restrict__ W3, const float* __restrict__ al3,
                       const float* __restrict__ ar3, float* __restrict__ wx1,
                       float* __restrict__ wx2, float* __restrict__ wx3,
                       const int* __restrict__ dst, int* __restrict__ deg, int n_edges) {
    if (blockIdx.x < 3) {
        int b = blockIdx.x;
        const float *W, *al, *ar;
        float* wx;
        int FIN, FOUT, H, D;
        if (b == 0) { W = W1; al = al1; ar = ar1; wx = wx1; FIN = 25; FOUT = 40; H = 4; D = 10; }
        else if (b == 1) { W = W2; al = al2; ar = ar2; wx = wx2; FIN = 40; FOUT = 100; H = 4; D = 25; }
        else { W = W3; al = al3; ar = ar3; wx = wx3; FIN = 100; FOUT = 50; H = 1; D = 50; }
        for (int i = threadIdx.x; i < FOUT * FIN; i += blockDim.x) wx[i] = W[i];
        for (int i = threadIdx.x; i < 2 * H * FIN; i += blockDim.x) {
            int row = i / FIN, k = i % FIN;
            int h = row % H, isR = row / H;
            const float* a = isR ? ar : al;
            float s = 0.f;
            for (int d = 0; d < D; ++d) s += W[(h * D + d) * FIN + k] * a[h * D + d];
            wx[(FOUT + isR * H + h) * FIN + k] = s;
        }
    } else {
        int e = (blockIdx.x - 3) * blockDim.x + threadIdx.x;
        if (e < n_edges) atomicAdd(&deg[dst[e]], 1);
    }
}

// ---- 3-kernel scan cascade (proven ~10us; single-block scan was 86us — do not merge)
__global__ void k_scan_block(const int* __restrict__ deg, int* __restrict__ incl,
                             int* __restrict__ blocksum, int n) {
    __shared__ int tmp[256];
    int t = threadIdx.x;
    int i = blockIdx.x * 256 + t;
    int v = (i < n) ? deg[i] : 0;
    tmp[t] = v;
    __syncthreads();
    for (int off = 1; off < 256; off <<= 1) {
        int add = (t >= off) ? tmp[t - off] : 0;
        __syncthreads();
        tmp[t] += add;
        __syncthreads();
    }
    if (i < n) incl[i] = tmp[t];
    if (t == 255) blocksum[blockIdx.x] = tmp[t];
}

__global__ void k_scan_top(const int* __restrict__ blocksum, int* __restrict__ blockoff, int nb) {
    __shared__ int tmp[256];
    int t = threadIdx.x;
    int base = 0;
    for (int c = 0; c < nb; c += 256) {
        int i = c + t;
        int v = (i < nb) ? blocksum[i] : 0;
        tmp[t] = v;
        __syncthreads();
        for (int off = 1; off < 256; off <<= 1) {
            int add = (t >= off) ? tmp[t - off] : 0;
            __syncthreads();
            tmp[t] += add;
            __syncthreads();
        }
        if (i < nb) blockoff[i] = base + tmp[t] - v;
        base += tmp[255];
        __syncthreads();
    }
}

__global__ void k_scan_finalize(const int* __restrict__ incl, const int* __restrict__ deg,
                                const int* __restrict__ blockoff, int* __restrict__ rowptr,
                                int n, int n_edges) {
    int i = blockIdx.x * blockDim.x + threadIdx.x;
    if (i < n) rowptr[i] = incl[i] - deg[i] + blockoff[i / 256];
    if (i == 0) rowptr[n] = n_edges;
}

// ---- fused linear + scores (layer 1 only): produces h, el, er from wext
template <int FIN, int FOUT, int H>
__global__ void k_linear(const float* __restrict__ x, const float* __restrict__ wx,
                         float* __restrict__ h, float* __restrict__ el, float* __restrict__ er,
                         int n_nodes) {
    constexpr int FOUTE = FOUT + 2 * H;
    __shared__ float Ws[FIN * FOUTE];
    for (int i = threadIdx.x; i < FIN * FOUTE; i += blockDim.x) {
        int f = i / FIN, k = i % FIN;
        Ws[k * FOUTE + f] = wx[i];
    }
    __syncthreads();
    int idx = blockIdx.x * blockDim.x + threadIdx.x;
    if (idx >= n_nodes * FOUTE) return;
    int n = idx / FOUTE, f = idx % FOUTE;
    const float* __restrict__ xr = x + (long long)n * FIN;
    float acc = 0.f;
#pragma unroll
    for (int k = 0; k < FIN; ++k) acc += xr[k] * Ws[k * FOUTE + f];
    if (f < FOUT) h[(long long)n * FOUT + f] = acc;
    else if (f < FOUT + H) el[n * H + (f - FOUT)] = acc;
    else er[n * H + (f - FOUT - H)] = acc;
}

__global__ void k_fill(const int* __restrict__ src, const int* __restrict__ dst,
                       const int* __restrict__ rowptr, int* __restrict__ cursor,
                       int* __restrict__ csr_src, int n_edges) {
    int e = blockIdx.x * blockDim.x + threadIdx.x;
    if (e >= n_edges) return;
    int d = dst[e];
    int pos = atomicAdd(&cursor[d], 1);
    csr_src[rowptr[d] + pos] = src[e];
}

// wave-parallel rank sort: one wave per node (deterministic sorted order).
__global__ void k_sort_wave(const int* __restrict__ rowptr, int* __restrict__ csr_src,
                            int n_nodes) {
    int wid = (blockIdx.x * blockDim.x + threadIdx.x) >> 6;
    int lane = threadIdx.x & 63;
    if (wid >= n_nodes) return;
    int s0 = rowptr[wid], e0 = rowptr[wid + 1];
    int d = e0 - s0;
    if (d <= 1) return;
    if (d <= 64) {
        int v = (lane < d) ? csr_src[s0 + lane] : 0x7FFFFFFF;
        int rank = 0;
        for (int k = 0; k < d; ++k) {
            int vk = __shfl(v, k);
            rank += (vk < v || (vk == v && k < lane)) ? 1 : 0;
        }
        if (lane < d) csr_src[s0 + rank] = v;
    } else if (lane == 0) {
        for (int a = s0 + 1; a < e0; ++a) {
            int key = csr_src[a];
            int b = a - 1;
            while (b >= s0 && csr_src[b] > key) { csr_src[b + 1] = csr_src[b]; --b; }
            csr_src[b + 1] = key;
        }
    }
}

// ================= fused gather(layer k) + linear(layer k+1) ==========================
// Gather body is r7's proven 78.4us form (do not touch: per-slot f-guards, flat hv,
// butterfly denom). Instead of writing xout to global, the wave stages its node's
// x-row in LDS (wave-synchronous) and computes the NEXT layer's linear+scores from the
// block-staged wext — per-node dependency only, so no grid sync needed.
// OUT_MODE 0: route FOUTE2 outputs to h2/el2/er2 (wext layout).
// OUT_MODE 1: final FC — out2[f2] = dot + fcb[f2], write to out2 (d_out).
template <int FOUT, int H, int D, int EB, int FOUTE2, int FOUT2, int H2, int OUT_MODE>
__global__ void k_gather_linear(const int* __restrict__ rowptr, const int* __restrict__ csr_src,
                                const float* __restrict__ el, const float* __restrict__ er,
                                const float* __restrict__ h, const float* __restrict__ bias,
                                const float* __restrict__ wx2, const float* __restrict__ fcb,
                                float* __restrict__ h2, float* __restrict__ el2,
                                float* __restrict__ er2, int n_nodes) {
    constexpr int NF = (FOUT + 63) / 64;
    constexpr int FIN2 = FOUT;
    constexpr int NR2 = (FOUTE2 + 63) / 64;
    __shared__ float Ws[FIN2 * FOUTE2];
    __shared__ float xrow[4][FIN2];
    for (int i = threadIdx.x; i < FIN2 * FOUTE2; i += blockDim.x) {
        int f = i / FIN2, k = i % FIN2;
        Ws[k * FOUTE2 + f] = wx2[i];
    }
    __syncthreads();  // only barrier; before any divergent return

    int wid = (blockIdx.x * blockDim.x + threadIdx.x) >> 6;
    int lane = threadIdx.x & 63;
    int wv = threadIdx.x >> 6;
    if (wid >= n_nodes) return;
    int start = rowptr[wid], end = rowptr[wid + 1];

    const int eidx = lane / H;
    const int hh_c = lane % H;
    const float er_c = er[wid * H + hh_c];

    float acc[NF];
    int f_i[NF], hh_i[NF];
#pragma unroll
    for (int r = 0; r < NF; ++r) {
        int f = lane + r * 64;
        f_i[r] = f;
        hh_i[r] = (f < FOUT) ? (f / D) : 0;
        acc[r] = 0.f;
    }
    float den_acc = 0.f;

    if (start < end) {
        int j0 = start;
        int nb = end - j0;
        if (nb > EB) nb = EB;
        int s_c = csr_src[j0 + (eidx < nb ? eidx : 0)];
        float e_c = el[s_c * H + hh_c];

        while (true) {
            int j1 = j0 + nb;
            int nbn = end - j1;
            if (nbn > EB) nbn = EB;
            int s_n = 0;
            float e_n = 0.f;
            if (nbn > 0) {  // prefetch next batch ids + el (hides latency under FMAs)
                s_n = csr_src[j1 + (eidx < nbn ? eidx : 0)];
                e_n = el[s_n * H + hh_c];
            }
            // probability (one per p-slot) + butterfly denominator
            float p_c = expf(lrelu(e_c + er_c));
            float pd = (eidx < nb) ? p_c : 0.f;
#pragma unroll
            for (int st = H; st < 64; st <<= 1) pd += __shfl_xor(pd, st);
            den_acc += pd;

            // burst-load edge rows into flat register buffer (static indexing)
            float hv[EB * NF];
#pragma unroll
            for (int e = 0; e < EB; ++e) {
                if (e < nb) {  // nb wave-uniform
                    int s = __shfl(s_c, e * H);
                    const float* __restrict__ hrow = h + (long long)s * FOUT;
#pragma unroll
                    for (int r = 0; r < NF; ++r)
                        if (f_i[r] < FOUT) hv[e * NF + r] = hrow[f_i[r]];
                }
            }
            // consume
#pragma unroll
            for (int e = 0; e < EB; ++e) {
                if (e < nb) {
#pragma unroll
                    for (int r = 0; r < NF; ++r) {
                        float p = __shfl(p_c, e * H + hh_i[r]);
                        if (f_i[r] < FOUT) acc[r] += p * hv[e * NF + r];
                    }
                }
            }
            if (nbn <= 0) break;
            j0 = j1;
            nb = nbn;
            s_c = s_n;
            e_c = e_n;
        }
    }

    // epilogue: den shfls hoisted outside the divergent f-guard; x-row -> LDS
    float den_r[NF];
#pragma unroll
    for (int r = 0; r < NF; ++r) den_r[r] = __shfl(den_acc, hh_i[r]);
#pragma unroll
    for (int r = 0; r < NF; ++r) {
        if (f_i[r] < FOUT) {
            float val;
            if (end > start) val = acc[r] / den_r[r] + bias[f_i[r]];
            else val = bias[f_i[r]];
            xrow[wv][f_i[r]] = val > 0.f ? val : 0.f;
        }
    }
    // wave-synchronous LDS write->read (compiler orders via lgkmcnt; no barrier needed)

    // ---- next-layer linear from LDS (k ascending — identical order to k_linear)
#pragma unroll
    for (int r2 = 0; r2 < NR2; ++r2) {
        int f2 = lane + r2 * 64;
        if (f2 < FOUTE2) {
            float a2 = (OUT_MODE == 1) ? fcb[f2] : 0.f;
            for (int k = 0; k < FIN2; ++k) a2 += xrow[wv][k] * Ws[k * FOUTE2 + f2];
            if (OUT_MODE == 1) {
                h2[(long long)wid * FOUTE2 + f2] = a2;
            } else {
                if (f2 < FOUT2) h2[(long long)wid * FOUT2 + f2] = a2;
                else if (f2 < FOUT2 + H2) el2[wid * H2 + (f2 - FOUT2)] = a2;
                else er2[wid * H2 + (f2 - FOUT2 - H2)] = a2;
            }
        }
    }
}

extern "C" void kernel_launch(void* const* d_in, const int* in_sizes, int n_in,
                              void* d_out, int out_size, void* d_ws, size_t ws_size,
                              hipStream_t stream) {
    const float* features = (const float*)d_in[0];
    const int* src = (const int*)d_in[1];
    const int* dst = (const int*)d_in[2];
    const float* W1 = (const float*)d_in[3];
    const float* al1 = (const float*)d_in[4];
    const float* ar1 = (const float*)d_in[5];
    const float* b1 = (const float*)d_in[6];
    const float* W2 = (const float*)d_in[7];
    const float* al2 = (const float*)d_in[8];
    const float* ar2 = (const float*)d_in[9];
    const float* b2 = (const float*)d_in[10];
    const float* W3 = (const float*)d_in[11];
    const float* al3 = (const float*)d_in[12];
    const float* ar3 = (const float*)d_in[13];
    const float* b3 = (const float*)d_in[14];
    const float* fc_w = (const float*)d_in[15];
    const float* fc_b = (const float*)d_in[16];

    const int n_nodes = in_sizes[0] / 25;  // 50000
    const int n_edges = in_sizes[1];       // 1000000
    const int nblocks_nodes = cdiv(n_nodes, 256);
    const int gather_blocks = cdiv((long long)n_nodes * 64, 256);

    char* ws = (char*)d_ws;
    size_t off = 0;
    auto alloc = [&](size_t bytes) {
        char* p = ws + off;
        off += (bytes + 255) & ~(size_t)255;
        return p;
    };
    float* hA = (float*)alloc((size_t)n_nodes * 100 * sizeof(float));
    float* hB = (float*)alloc((size_t)n_nodes * 100 * sizeof(float));
    float* el0 = (float*)alloc((size_t)n_nodes * 4 * sizeof(float));
    float* er0 = (float*)alloc((size_t)n_nodes * 4 * sizeof(float));
    float* el1 = (float*)alloc((size_t)n_nodes * 4 * sizeof(float));
    float* er1 = (float*)alloc((size_t)n_nodes * 4 * sizeof(float));
    int* degcur = (int*)alloc((size_t)2 * n_nodes * sizeof(int));  // deg | cursor
    int* deg = degcur;
    int* cursor = degcur + n_nodes;
    int* incl = (int*)alloc((size_t)n_nodes * sizeof(int));
    int* blocksum = (int*)alloc((size_t)nblocks_nodes * sizeof(int));
    int* blockoff = (int*)alloc((size_t)nblocks_nodes * sizeof(int));
    int* rowptr = (int*)alloc((size_t)(n_nodes + 1) * sizeof(int));
    int* csr_src = (int*)alloc((size_t)n_edges * sizeof(int));
    float* wx1 = (float*)alloc((size_t)48 * 25 * sizeof(float));
    float* wx2 = (float*)alloc((size_t)108 * 40 * sizeof(float));
    float* wx3 = (float*)alloc((size_t)52 * 100 * sizeof(float));
    (void)ws_size;

    // ---- prep: zero deg/cursor, then wext (blocks 0-2) + degree count (blocks 3+)
    hipMemsetAsync(degcur, 0, (size_t)2 * n_nodes * sizeof(int), stream);
    k_prep<<<3 + cdiv(n_edges, 256), 256, 0, stream>>>(W1, al1, ar1, W2, al2, ar2, W3, al3,
                                                       ar3, wx1, wx2, wx3, dst, deg, n_edges);
    k_scan_block<<<nblocks_nodes, 256, 0, stream>>>(deg, incl, blocksum, n_nodes);
    k_scan_top<<<1, 256, 0, stream>>>(blocksum, blockoff, nblocks_nodes);
    k_scan_finalize<<<cdiv(n_nodes + 1, 256), 256, 0, stream>>>(incl, deg, blockoff, rowptr,
                                                                n_nodes, n_edges);
    k_fill<<<cdiv(n_edges, 256), 256, 0, stream>>>(src, dst, rowptr, cursor, csr_src, n_edges);
    k_sort_wave<<<gather_blocks, 256, 0, stream>>>(rowptr, csr_src, n_nodes);

    // ---- layer 1 linear (standalone): features -> hA, el0, er0
    k_linear<25, 40, 4><<<cdiv((long long)n_nodes * 48, 256), 256, 0, stream>>>(
        features, wx1, hA, el0, er0, n_nodes);

    // ---- fused gather1 + linear2: (hA, el0, er0) -> (hB, el1, er1)
    k_gather_linear<40, 4, 10, 16, 108, 100, 4, 0><<<gather_blocks, 256, 0, stream>>>(
        rowptr, csr_src, el0, er0, hA, b1, wx2, nullptr, hB, el1, er1, n_nodes);

    // ---- fused gather2 + linear3: (hB, el1, er1) -> (hA, el0, er0)
    k_gather_linear<100, 4, 25, 16, 52, 50, 1, 0><<<gather_blocks, 256, 0, stream>>>(
        rowptr, csr_src, el1, er1, hB, b2, wx3, nullptr, hA, el0, er0, n_nodes);

    // ---- fused gather3 + FC: (hA, el0, er0) -> d_out
    k_gather_linear<50, 1, 50, 32, 93, 93, 0, 1><<<gather_blocks, 256, 0, stream>>>(
        rowptr, csr_src, el0, er0, hA, b3, fc_w, fc_b, (float*)d_out, nullptr, nullptr,
        n_nodes);
}